// Round 2
// baseline (624.975 us; speedup 1.0000x reference)
//
#include <hip/hip_runtime.h>

// Problem constants (match reference)
#define RB        32      // rows per block
#define NT        512     // threads per block (8 waves)
#define DEEP_IN   164     // 64 user + 64 item + 32 cat + 2 price + 2 temporal
#define H1        128
#define H2        64
#define H3        32
#define DIM2_C    10000

// LDS arena (floats), no aliasing:
//   xs  : [0,     5248)   32 x 164 row-major
//   h1  : [5248,  9344)   32 x 128, float4-chunk XOR swizzle (kc ^ (r&7))
//   h2  : [9344, 11392)   32 x 64,  same swizzle
//   h3  : [11392,12416)   32 x 32,  same swizzle
//   wide: [12416,12448)
// total 12448 f = 49.8 KB -> 2 blocks/CU fits (99.6 KB < 160 KB)
#define XS_OFF   0
#define H1_OFF   5248
#define H2_OFF   9344
#define H3_OFF   11392
#define WIDE_OFF 12416
#define ARENA_F  12448

__global__ __launch_bounds__(NT, 4) void wad_fused(
    const float* __restrict__ user, const float* __restrict__ price,
    const float* __restrict__ temporal, const float* __restrict__ item_emb,
    const float* __restrict__ cat_emb, const float* __restrict__ we1,
    const float* __restrict__ we2, const float* __restrict__ crossW,
    const int* __restrict__ item_ids, const int* __restrict__ cat_ids,
    const int* __restrict__ wf1, const int* __restrict__ wf2,
    const float* __restrict__ W1, const float* __restrict__ b1,
    const float* __restrict__ W2, const float* __restrict__ b2,
    const float* __restrict__ W3, const float* __restrict__ b3,
    const float* __restrict__ W4, const float* __restrict__ b4,
    const float* __restrict__ g1, const float* __restrict__ be1,
    const float* __restrict__ g2, const float* __restrict__ be2,
    const float* __restrict__ g3, const float* __restrict__ be3,
    float* __restrict__ out)
{
    __shared__ float arena[ARENA_F];
    float* xs    = arena + XS_OFF;
    float* h1    = arena + H1_OFF;
    float* h2    = arena + H2_OFF;
    float* h3    = arena + H3_OFF;
    float* wideS = arena + WIDE_OFF;

    const int tid  = threadIdx.x;
    const int lane = tid & 63;
    const int wave = tid >> 6;          // 0..7
    const int r    = lane & 31;         // row within tile
    const int h    = lane >> 5;         // 0/1 col-half within wave
    const int r0   = blockIdx.x * RB;

    const float bn_rs = rsqrtf(1.0f + 1e-5f);

    // ---------------- phase 0: gather X tile (vectorized) + wide term ----------------
    {
        int gr = tid >> 4;              // 0..31 row
        int q  = tid & 15;              // float4 slot
        int R  = r0 + gr;
        float4* dst = (float4*)(xs + gr * DEEP_IN);   // 164 = 41 float4, 16B aligned
        const float4* up = (const float4*)(user + (size_t)R * 64);
        dst[q] = up[q];
        int iid = item_ids[R];
        const float4* ip = (const float4*)(item_emb + (size_t)iid * 64);
        dst[16 + q] = ip[q];
        if (q < 8) {
            int cid = cat_ids[R];
            dst[32 + q] = ((const float4*)(cat_emb + (size_t)cid * 32))[q];
        } else if (q == 8) {
            float2 p  = *(const float2*)(price + (size_t)R * 2);
            float2 t2 = *(const float2*)(temporal + (size_t)R * 2);
            dst[40] = make_float4(p.x, p.y, t2.x, t2.y);
        }
    }
    if (tid < RB) {
        int R = r0 + tid;
        int f1 = wf1[R], f2 = wf2[R];
        wideS[tid] = we1[f1] + we2[f2] + crossW[f1 * DIM2_C + f2];
    }
    __syncthreads();

    // ---------------- layer 1: [164] -> [128]; lane owns (row r, cols c0..c0+7) ----------------
    {
        const int c0 = wave * 16 + h * 8;
        float acc[8];
#pragma unroll
        for (int n = 0; n < 8; ++n) acc[n] = 0.0f;
        const float* xrow  = xs + r * DEEP_IN;
        const float* wbase = W1 + c0;
#pragma unroll 2
        for (int kq = 0; kq < DEEP_IN / 4; ++kq) {
            float4 a = *(const float4*)(xrow + kq * 4);
#pragma unroll
            for (int kk = 0; kk < 4; ++kk) {
                const float* wk = wbase + (kq * 4 + kk) * H1;
                float4 w0 = *(const float4*)(wk);
                float4 w1 = *(const float4*)(wk + 4);
                float av = ((const float*)&a)[kk];
                acc[0] += av * w0.x; acc[1] += av * w0.y;
                acc[2] += av * w0.z; acc[3] += av * w0.w;
                acc[4] += av * w1.x; acc[5] += av * w1.y;
                acc[6] += av * w1.z; acc[7] += av * w1.w;
            }
        }
        // epilogue: bias + eval-BN + relu, store swizzled
        float4 bb0 = *(const float4*)(b1 + c0), bb1 = *(const float4*)(b1 + c0 + 4);
        float4 gg0 = *(const float4*)(g1 + c0), gg1 = *(const float4*)(g1 + c0 + 4);
        float4 ee0 = *(const float4*)(be1 + c0), ee1 = *(const float4*)(be1 + c0 + 4);
        float4 o0, o1;
        o0.x = fmaxf((acc[0] + bb0.x) * (gg0.x * bn_rs) + ee0.x, 0.0f);
        o0.y = fmaxf((acc[1] + bb0.y) * (gg0.y * bn_rs) + ee0.y, 0.0f);
        o0.z = fmaxf((acc[2] + bb0.z) * (gg0.z * bn_rs) + ee0.z, 0.0f);
        o0.w = fmaxf((acc[3] + bb0.w) * (gg0.w * bn_rs) + ee0.w, 0.0f);
        o1.x = fmaxf((acc[4] + bb1.x) * (gg1.x * bn_rs) + ee1.x, 0.0f);
        o1.y = fmaxf((acc[5] + bb1.y) * (gg1.y * bn_rs) + ee1.y, 0.0f);
        o1.z = fmaxf((acc[6] + bb1.z) * (gg1.z * bn_rs) + ee1.z, 0.0f);
        o1.w = fmaxf((acc[7] + bb1.w) * (gg1.w * bn_rs) + ee1.w, 0.0f);
        int kc = c0 >> 2;                       // chunk base (c0/4)
        *(float4*)(h1 + r * H1 + ((kc    ) ^ (r & 7)) * 4) = o0;
        *(float4*)(h1 + r * H1 + ((kc + 1) ^ (r & 7)) * 4) = o1;
    }
    __syncthreads();

    // ---------------- layer 2: [128] -> [64]; lane owns (row r, cols c2..c2+3) ----------------
    {
        const int c2 = wave * 8 + h * 4;
        float acc2[4];
#pragma unroll
        for (int n = 0; n < 4; ++n) acc2[n] = 0.0f;
#pragma unroll 2
        for (int kq = 0; kq < H1 / 4; ++kq) {
            int kcs = kq ^ (r & 7);
            float4 a = *(const float4*)(h1 + r * H1 + kcs * 4);
#pragma unroll
            for (int kk = 0; kk < 4; ++kk) {
                float4 w = *(const float4*)(W2 + (kq * 4 + kk) * H2 + c2);
                float av = ((const float*)&a)[kk];
                acc2[0] += av * w.x; acc2[1] += av * w.y;
                acc2[2] += av * w.z; acc2[3] += av * w.w;
            }
        }
        float4 bb = *(const float4*)(b2 + c2);
        float4 gg = *(const float4*)(g2 + c2);
        float4 ee = *(const float4*)(be2 + c2);
        float4 o;
        o.x = fmaxf((acc2[0] + bb.x) * (gg.x * bn_rs) + ee.x, 0.0f);
        o.y = fmaxf((acc2[1] + bb.y) * (gg.y * bn_rs) + ee.y, 0.0f);
        o.z = fmaxf((acc2[2] + bb.z) * (gg.z * bn_rs) + ee.z, 0.0f);
        o.w = fmaxf((acc2[3] + bb.w) * (gg.w * bn_rs) + ee.w, 0.0f);
        int kc = c2 >> 2;                       // = wave*2 + h, 0..15
        *(float4*)(h2 + r * H2 + (kc ^ (r & 7)) * 4) = o;
    }
    __syncthreads();

    // ---------------- layer 3: [64] -> [32]; lane owns (row r, cols c3..c3+1) ----------------
    {
        const int c3 = wave * 4 + h * 2;
        float a0 = 0.0f, a1 = 0.0f;
#pragma unroll 2
        for (int kq = 0; kq < H2 / 4; ++kq) {
            int kcs = kq ^ (r & 7);
            float4 a = *(const float4*)(h2 + r * H2 + kcs * 4);
#pragma unroll
            for (int kk = 0; kk < 4; ++kk) {
                float2 w = *(const float2*)(W3 + (kq * 4 + kk) * H3 + c3);
                float av = ((const float*)&a)[kk];
                a0 += av * w.x; a1 += av * w.y;
            }
        }
        float z0 = fmaxf((a0 + b3[c3])     * (g3[c3]     * bn_rs) + be3[c3],     0.0f);
        float z1 = fmaxf((a1 + b3[c3 + 1]) * (g3[c3 + 1] * bn_rs) + be3[c3 + 1], 0.0f);
        // chunk kc = c3>>2 = wave, sub-offset h*2
        float2 o2 = make_float2(z0, z1);
        *(float2*)(h3 + r * H3 + (wave ^ (r & 7)) * 4 + h * 2) = o2;
    }
    __syncthreads();

    // ---------------- layer 4 + wide: [32] -> [1] ----------------
    if (tid < RB) {
        int j = tid;
        float s = b4[0];
#pragma unroll
        for (int kq = 0; kq < H3 / 4; ++kq) {
            int kcs = kq ^ (j & 7);
            float4 a = *(const float4*)(h3 + j * H3 + kcs * 4);
            s += ((const float*)&a)[0] * W4[kq * 4 + 0];
            s += ((const float*)&a)[1] * W4[kq * 4 + 1];
            s += ((const float*)&a)[2] * W4[kq * 4 + 2];
            s += ((const float*)&a)[3] * W4[kq * 4 + 3];
        }
        out[r0 + j] = s + wideS[j];
    }
}

extern "C" void kernel_launch(void* const* d_in, const int* in_sizes, int n_in,
                              void* d_out, int out_size, void* d_ws, size_t ws_size,
                              hipStream_t stream) {
    const float* user     = (const float*)d_in[0];
    const float* price    = (const float*)d_in[1];
    const float* temporal = (const float*)d_in[2];
    const float* item_emb = (const float*)d_in[3];
    const float* cat_emb  = (const float*)d_in[4];
    const float* we1      = (const float*)d_in[5];
    const float* we2      = (const float*)d_in[6];
    const float* crossW   = (const float*)d_in[7];
    const int*   item_ids = (const int*)d_in[8];
    const int*   cat_ids  = (const int*)d_in[9];
    const int*   wf1      = (const int*)d_in[10];
    const int*   wf2      = (const int*)d_in[11];
    const float* W1 = (const float*)d_in[12];
    const float* b1 = (const float*)d_in[13];
    const float* W2 = (const float*)d_in[14];
    const float* b2 = (const float*)d_in[15];
    const float* W3 = (const float*)d_in[16];
    const float* b3 = (const float*)d_in[17];
    const float* W4 = (const float*)d_in[18];
    const float* b4 = (const float*)d_in[19];
    const float* g1  = (const float*)d_in[20];
    const float* be1 = (const float*)d_in[21];
    const float* g2  = (const float*)d_in[22];
    const float* be2 = (const float*)d_in[23];
    const float* g3  = (const float*)d_in[24];
    const float* be3 = (const float*)d_in[25];
    float* out = (float*)d_out;

    const int nblocks = 16384 / RB;   // 512 blocks -> 2 blocks/CU, 4 waves/SIMD
    wad_fused<<<nblocks, NT, 0, stream>>>(
        user, price, temporal, item_emb, cat_emb, we1, we2, crossW,
        item_ids, cat_ids, wf1, wf2,
        W1, b1, W2, b2, W3, b3, W4, b4,
        g1, be1, g2, be2, g3, be3, out);
}